// Round 8
// baseline (1820.947 us; speedup 1.0000x reference)
//
#include <hip/hip_runtime.h>
#include <stdint.h>

// GRU encoder B=512,T=512,H=256,IN=2 — R7: raw-asm MFMA, B operand direct
// from AGPR. R6 post-mortem: the MFMA *intrinsic* can't take AGPR inputs ->
// compiler emitted 4 v_accvgpr_read per MFMA (192/step, the VALU storm) and
// arch VGPRs hit 128 (320 total -> occupancy fell to ~1 wave/SIMD anyway).
// Here: launch_bounds(512,1) (192 AGPR + ~85 VGPR of 512, no spill), per-tile
// asm chains of 8 v_mfma_f32_16x16x32_f16 with a[] B-fragments, s_nop fence
// before VALU reads D. h16 batch stride padded 256->288 halves (bank split).

typedef _Float16 v8h  __attribute__((ext_vector_type(8)));
typedef float    f32x4 __attribute__((ext_vector_type(4)));

#define BB 512
#define TT 512
#define HH 256
#define NT 48    // 768/16 col tiles
#define KT 8     // 256/32 k tiles
#define HSTR 288 // padded h16 stride (halves): batch0/1 -> disjoint LDS banks

// Wp4[(ct*KT + kt)*64 + lane] = 8 halves W_hh[16ct + (lane&15)][32kt + (lane>>4)*8 + j]
__global__ void prep_pack(const float* __restrict__ Whh, uint4* __restrict__ Wp4) {
    int n = blockIdx.x * blockDim.x + threadIdx.x;   // [0, 24576)
    int lane = n & 63;
    int kt = (n >> 6) & (KT - 1);
    int ct = n >> 9;
    int row = 16 * ct + (lane & 15);
    int k0  = 32 * kt + (lane >> 4) * 8;
    const float* src = Whh + (size_t)row * HH + k0;
    v8h v;
    #pragma unroll
    for (int j = 0; j < 8; ++j) v[j] = (_Float16)src[j];
    Wp4[n] = __builtin_bit_cast(uint4, v);
}

__device__ __forceinline__ float sigmoid_f(float x) {
    return __builtin_amdgcn_rcpf(1.f + __expf(-x));
}
__device__ __forceinline__ float tanh_f(float x) {
    x = fminf(fmaxf(x, -15.f), 15.f);
    float e = __expf(-2.f * x);
    return (1.f - e) * __builtin_amdgcn_rcpf(1.f + e);
}

// 8 chained MFMAs for one 16-col tile: D = sum_kt A[kt] * W[kt], C seeded 0.
#define MFMA_TILE(D, Z, W)                                                   \
    asm volatile(                                                            \
        "v_mfma_f32_16x16x32_f16 %0, %2, %10, %1\n\t"                        \
        "v_mfma_f32_16x16x32_f16 %0, %3, %11, %0\n\t"                        \
        "v_mfma_f32_16x16x32_f16 %0, %4, %12, %0\n\t"                        \
        "v_mfma_f32_16x16x32_f16 %0, %5, %13, %0\n\t"                        \
        "v_mfma_f32_16x16x32_f16 %0, %6, %14, %0\n\t"                        \
        "v_mfma_f32_16x16x32_f16 %0, %7, %15, %0\n\t"                        \
        "v_mfma_f32_16x16x32_f16 %0, %8, %16, %0\n\t"                        \
        "v_mfma_f32_16x16x32_f16 %0, %9, %17, %0"                            \
        : "=&v"(D)                                                           \
        : "v"(Z), "v"(a0), "v"(a1), "v"(a2), "v"(a3),                        \
          "v"(a4), "v"(a5), "v"(a6), "v"(a7),                                \
          "a"(W[0]), "a"(W[1]), "a"(W[2]), "a"(W[3]),                        \
          "a"(W[4]), "a"(W[5]), "a"(W[6]), "a"(W[7]))

__global__ void __launch_bounds__(512, 1)
gru_persist(const float* __restrict__ x,        // [B,T,2]
            const int* __restrict__ len,        // [B]
            const float* __restrict__ h0,       // [B,H]
            const float* __restrict__ Wih,      // [768,2]
            const float* __restrict__ bih,      // [768]
            const float* __restrict__ bhh,      // [768]
            const uint4* __restrict__ Wp4,      // MFMA-fragment-packed fp16 W_hh
            float* __restrict__ out)            // [B,H]
{
    __shared__ __align__(16) _Float16 h16[2][2][HSTR];  // [buf][batch][e]
    const int tid  = threadIdx.x;
    const int lane = tid & 63;
    const int w    = tid >> 6;          // wave 0..7
    const int b0   = blockIdx.x * 2;

    // ---- W B-fragments for this wave's 6 tiles, pinned in AGPRs ----
    v8h wfr[6][KT];
    {
        const int cts[6] = {2*w, 2*w+1, 16+2*w, 16+2*w+1, 32+2*w, 32+2*w+1};
        #pragma unroll
        for (int c = 0; c < 6; ++c)
            #pragma unroll
            for (int kt = 0; kt < KT; ++kt)
                wfr[c][kt] = __builtin_bit_cast(v8h, Wp4[(cts[c] * KT + kt) * 64 + lane]);
    }
    #pragma unroll
    for (int c = 0; c < 6; ++c)
        #pragma unroll
        for (int kt = 0; kt < KT; ++kt)
            asm volatile("" : "+a"(wfr[c][kt]));    // AGPR-resident, not remat

    // ---- gate-lane state: element e = 32w + (lane&31), both batches ----
    const int e = 32 * w + (lane & 31);
    float cR = bih[e] + bhh[e];
    float cZ = bih[HH + e] + bhh[HH + e];
    float cN = bih[2 * HH + e];
    float dN = bhh[2 * HH + e];
    float wR0 = Wih[2 * e],            wR1 = Wih[2 * e + 1];
    float wZ0 = Wih[2 * (HH + e)],     wZ1 = Wih[2 * (HH + e) + 1];
    float wN0 = Wih[2 * (2 * HH + e)], wN1 = Wih[2 * (2 * HH + e) + 1];
    float hp0 = h0[b0 * HH + e];
    float hp1 = h0[(b0 + 1) * HH + e];
    asm volatile("" : "+v"(cR), "+v"(cZ), "+v"(cN), "+v"(dN));
    asm volatile("" : "+v"(wR0), "+v"(wR1), "+v"(wZ0), "+v"(wZ1));
    asm volatile("" : "+v"(wN0), "+v"(wN1));

    if (lane < 32) {
        h16[0][0][e] = (_Float16)hp0;
        h16[0][1][e] = (_Float16)hp1;
    }

    const int l0 = len[b0], l1 = len[b0 + 1];
    const int lm = l0 > l1 ? l0 : l1;
    const float* xb0 = x + (size_t)b0 * TT * 2;
    const float* xb1 = x + (size_t)(b0 + 1) * TT * 2;

    // A-frag source: row m=lane&15 -> batch m&1=lane&1, k chunk=(lane>>4)*8
    const _Float16* abase = &h16[0][lane & 1][(lane >> 4) * 8];

    f32x4 zz = {0.f, 0.f, 0.f, 0.f};
    asm volatile("" : "+v"(zz));        // pinned zero C-seed

    __syncthreads();

    #pragma unroll 1
    for (int s = 0; s < lm; ++s) {
        const float2 xv0 = *(const float2*)(xb0 + 2 * s);
        const float2 xv1 = *(const float2*)(xb1 + 2 * s);

        const _Float16* ap = abase + (s & 1) * (2 * HSTR);   // h16 ping-pong
        const v8h a0 = *(const v8h*)(ap + 0 * 32);   // ds_read_b128 broadcast
        const v8h a1 = *(const v8h*)(ap + 1 * 32);
        const v8h a2 = *(const v8h*)(ap + 2 * 32);
        const v8h a3 = *(const v8h*)(ap + 3 * 32);
        const v8h a4 = *(const v8h*)(ap + 4 * 32);
        const v8h a5 = *(const v8h*)(ap + 5 * 32);
        const v8h a6 = *(const v8h*)(ap + 6 * 32);
        const v8h a7 = *(const v8h*)(ap + 7 * 32);

        f32x4 d0, d1, d2, d3, d4, d5;
        MFMA_TILE(d0, zz, wfr[0]);
        MFMA_TILE(d1, zz, wfr[1]);
        MFMA_TILE(d2, zz, wfr[2]);
        MFMA_TILE(d3, zz, wfr[3]);
        MFMA_TILE(d4, zz, wfr[4]);
        MFMA_TILE(d5, zz, wfr[5]);
        // MFMA->VALU/DS read-of-D hazard fence (asm is opaque to the
        // compiler's hazard recognizer): ~16 wait cycles.
        asm volatile("s_nop 7\n\ts_nop 7"
                     : "+v"(d0), "+v"(d1), "+v"(d2), "+v"(d3), "+v"(d4), "+v"(d5));

        // D layout: col=lane&15, rows 0/1 (regs 0/1) on lanes 0-15 = batches.
        // Move odd-tile results (elements 32w+16+c) to lanes 16-31.
        const float sR0 = __shfl_up(d1[0], 16), sR1 = __shfl_up(d1[1], 16);
        const float sZ0 = __shfl_up(d3[0], 16), sZ1 = __shfl_up(d3[1], 16);
        const float sN0 = __shfl_up(d5[0], 16), sN1 = __shfl_up(d5[1], 16);
        const bool hi = (lane & 16) != 0;
        const float uR0 = hi ? sR0 : d0[0], uR1 = hi ? sR1 : d0[1];
        const float uZ0 = hi ? sZ0 : d2[0], uZ1 = hi ? sZ1 : d2[1];
        const float uN0 = hi ? sN0 : d4[0], uN1 = hi ? sN1 : d4[1];

        if (lane < 32) {
            const float r0 = sigmoid_f(uR0 + fmaf(xv0.x, wR0, fmaf(xv0.y, wR1, cR)));
            const float z0 = sigmoid_f(uZ0 + fmaf(xv0.x, wZ0, fmaf(xv0.y, wZ1, cZ)));
            const float n0 = tanh_f(fmaf(xv0.x, wN0, fmaf(xv0.y, wN1, cN)) + r0 * (uN0 + dN));
            float hn0 = fmaf(z0, hp0 - n0, n0);
            const float r1 = sigmoid_f(uR1 + fmaf(xv1.x, wR0, fmaf(xv1.y, wR1, cR)));
            const float z1 = sigmoid_f(uZ1 + fmaf(xv1.x, wZ0, fmaf(xv1.y, wZ1, cZ)));
            const float n1 = tanh_f(fmaf(xv1.x, wN0, fmaf(xv1.y, wN1, cN)) + r1 * (uN1 + dN));
            float hn1 = fmaf(z1, hp1 - n1, n1);

            hn0 = (s < l0) ? hn0 : hp0;    // freeze finished batches
            hn1 = (s < l1) ? hn1 : hp1;
            const int nb = (s & 1) ^ 1;
            h16[nb][0][e] = (_Float16)hn0;
            h16[nb][1][e] = (_Float16)hn1;
            hp0 = hn0;
            hp1 = hn1;
            if (s == l0 - 1) out[b0 * HH + e] = hn0;
            if (s == l1 - 1) out[(b0 + 1) * HH + e] = hn1;
        }
        __syncthreads();   // new h16 buffer visible for next step's A reads
    }
}

extern "C" void kernel_launch(void* const* d_in, const int* in_sizes, int n_in,
                              void* d_out, int out_size, void* d_ws, size_t ws_size,
                              hipStream_t stream) {
    const float* x    = (const float*)d_in[0];
    const int*   lenp = (const int*)d_in[1];
    const float* h0   = (const float*)d_in[2];
    const float* Wih  = (const float*)d_in[3];
    const float* Whh  = (const float*)d_in[4];
    const float* bih  = (const float*)d_in[5];
    const float* bhh  = (const float*)d_in[6];
    float* out = (float*)d_out;

    uint4* Wp4 = (uint4*)d_ws;   // 384 KB scratch

    prep_pack<<<NT * KT * 64 / 256, 256, 0, stream>>>(Whh, Wp4);
    gru_persist<<<BB / 2, 512, 0, stream>>>(x, lenp, h0, Wih, bih, bhh, Wp4, out);
}

// Round 9
// 653.773 us; speedup vs baseline: 2.7853x; 2.7853x over previous
//
#include <hip/hip_runtime.h>
#include <stdint.h>

// GRU encoder B=512,T=512,H=256,IN=2 — R8: W pinned in *arch VGPRs*, MFMA
// intrinsics (no asm). R7 lesson: raw-asm "a" operands -> RA spills W to
// scratch (26 MB writes, 3x regress). R6 lesson: "+a" pin + intrinsic ->
// 192 v_accvgpr_read/step storm. Fix: 192 W dwords fit the 256-arch-VGPR cap
// if the rest is squeezed: launch_bounds(512,1), gate constants in LDS,
// kt-outer loop (1 A-frag live), D accums free to land in AGPR (native for
// MFMA D; only 12 reads/step back). h16 padded stride 288 (R7: 0 conflicts).

typedef _Float16 v8h  __attribute__((ext_vector_type(8)));
typedef float    f32x4 __attribute__((ext_vector_type(4)));

#define BB 512
#define TT 512
#define HH 256
#define NT 48    // 768/16 col tiles
#define KT 8     // 256/32 k tiles
#define HSTR 288 // padded h16 stride (halves): batch0/1 -> disjoint banks

// Wp4[(ct*KT + kt)*64 + lane] = 8 halves W_hh[16ct + (lane&15)][32kt + (lane>>4)*8 + j]
__global__ void prep_pack(const float* __restrict__ Whh, uint4* __restrict__ Wp4) {
    int n = blockIdx.x * blockDim.x + threadIdx.x;   // [0, 24576)
    int lane = n & 63;
    int kt = (n >> 6) & (KT - 1);
    int ct = n >> 9;
    int row = 16 * ct + (lane & 15);
    int k0  = 32 * kt + (lane >> 4) * 8;
    const float* src = Whh + (size_t)row * HH + k0;
    v8h v;
    #pragma unroll
    for (int j = 0; j < 8; ++j) v[j] = (_Float16)src[j];
    Wp4[n] = __builtin_bit_cast(uint4, v);
}

__device__ __forceinline__ float sigmoid_f(float x) {
    return __builtin_amdgcn_rcpf(1.f + __expf(-x));
}
__device__ __forceinline__ float tanh_f(float x) {
    x = fminf(fmaxf(x, -15.f), 15.f);
    float e = __expf(-2.f * x);
    return (1.f - e) * __builtin_amdgcn_rcpf(1.f + e);
}

__global__ void __launch_bounds__(512, 1)
gru_persist(const float* __restrict__ x,        // [B,T,2]
            const int* __restrict__ len,        // [B]
            const float* __restrict__ h0,       // [B,H]
            const float* __restrict__ Wih,      // [768,2]
            const float* __restrict__ bih,      // [768]
            const float* __restrict__ bhh,      // [768]
            const uint4* __restrict__ Wp4,      // MFMA-fragment-packed fp16 W_hh
            float* __restrict__ out)            // [B,H]
{
    __shared__ __align__(16) _Float16 h16[2][2][HSTR];  // [buf][batch][e]
    __shared__ float4 cst4[HH];   // cR,cZ,cN,dN
    __shared__ float4 wx4[HH];    // wR0,wR1,wZ0,wZ1
    __shared__ float2 wn2[HH];    // wN0,wN1

    const int tid  = threadIdx.x;
    const int lane = tid & 63;
    const int w    = tid >> 6;          // wave 0..7
    const int b0   = blockIdx.x * 2;

    // ---- W B-fragments for this wave's 6 tiles: 192 dwords in ARCH VGPRs ----
    v8h wfr[6][KT];
    {
        const int cts[6] = {2*w, 2*w+1, 16+2*w, 16+2*w+1, 32+2*w, 32+2*w+1};
        #pragma unroll
        for (int c = 0; c < 6; ++c)
            #pragma unroll
            for (int kt = 0; kt < KT; ++kt)
                wfr[c][kt] = __builtin_bit_cast(v8h, Wp4[(cts[c] * KT + kt) * 64 + lane]);
    }
    #pragma unroll
    for (int c = 0; c < 6; ++c)
        #pragma unroll
        for (int kt = 0; kt < KT; ++kt)
            asm volatile("" : "+v"(wfr[c][kt]));   // VGPR-resident, not remat

    // ---- per-element gate constants into LDS (saves ~10 arch VGPRs) ----
    if (tid < HH) {
        const int e2 = tid;
        cst4[e2] = float4{bih[e2] + bhh[e2], bih[HH + e2] + bhh[HH + e2],
                          bih[2 * HH + e2], bhh[2 * HH + e2]};
        wx4[e2] = float4{Wih[2 * e2], Wih[2 * e2 + 1],
                         Wih[2 * (HH + e2)], Wih[2 * (HH + e2) + 1]};
        wn2[e2] = float2{Wih[2 * (2 * HH + e2)], Wih[2 * (2 * HH + e2) + 1]};
    }

    // ---- gate-lane state: element e = 32w + (lane&31), both batches ----
    const int e = 32 * w + (lane & 31);
    float hp0 = h0[b0 * HH + e];
    float hp1 = h0[(b0 + 1) * HH + e];
    if (lane < 32) {
        h16[0][0][e] = (_Float16)hp0;
        h16[0][1][e] = (_Float16)hp1;
    }

    const int l0 = len[b0], l1 = len[b0 + 1];
    const int lm = l0 > l1 ? l0 : l1;
    const float* xb0 = x + (size_t)b0 * TT * 2;
    const float* xb1 = x + (size_t)(b0 + 1) * TT * 2;

    // A-frag source: row m=lane&15 -> batch m&1=lane&1, k chunk=(lane>>4)*8
    const _Float16* abase = &h16[0][lane & 1][(lane >> 4) * 8];

    __syncthreads();

    #pragma unroll 1
    for (int s = 0; s < lm; ++s) {
        const float2 xv0 = *(const float2*)(xb0 + 2 * s);
        const float2 xv1 = *(const float2*)(xb1 + 2 * s);

        const _Float16* ap = abase + (s & 1) * (2 * HSTR);  // h16 ping-pong
        f32x4 d0 = {0.f,0.f,0.f,0.f}, d1 = {0.f,0.f,0.f,0.f}, d2 = {0.f,0.f,0.f,0.f};
        f32x4 d3 = {0.f,0.f,0.f,0.f}, d4 = {0.f,0.f,0.f,0.f}, d5 = {0.f,0.f,0.f,0.f};
        #pragma unroll
        for (int kt = 0; kt < KT; ++kt) {     // kt-outer: one A-frag live
            const v8h a = *(const v8h*)(ap + kt * 32);   // ds_read_b128 broadcast
            d0 = __builtin_amdgcn_mfma_f32_16x16x32_f16(a, wfr[0][kt], d0, 0, 0, 0);
            d1 = __builtin_amdgcn_mfma_f32_16x16x32_f16(a, wfr[1][kt], d1, 0, 0, 0);
            d2 = __builtin_amdgcn_mfma_f32_16x16x32_f16(a, wfr[2][kt], d2, 0, 0, 0);
            d3 = __builtin_amdgcn_mfma_f32_16x16x32_f16(a, wfr[3][kt], d3, 0, 0, 0);
            d4 = __builtin_amdgcn_mfma_f32_16x16x32_f16(a, wfr[4][kt], d4, 0, 0, 0);
            d5 = __builtin_amdgcn_mfma_f32_16x16x32_f16(a, wfr[5][kt], d5, 0, 0, 0);
        }

        // D layout: col=lane&15, rows 0/1 (regs 0/1) on lanes 0-15 = batches.
        // Move odd-tile results (elements 32w+16+c) to lanes 16-31.
        const float sR0 = __shfl_up(d1[0], 16), sR1 = __shfl_up(d1[1], 16);
        const float sZ0 = __shfl_up(d3[0], 16), sZ1 = __shfl_up(d3[1], 16);
        const float sN0 = __shfl_up(d5[0], 16), sN1 = __shfl_up(d5[1], 16);
        const bool hi = (lane & 16) != 0;
        const float uR0 = hi ? sR0 : d0[0], uR1 = hi ? sR1 : d0[1];
        const float uZ0 = hi ? sZ0 : d2[0], uZ1 = hi ? sZ1 : d2[1];
        const float uN0 = hi ? sN0 : d4[0], uN1 = hi ? sN1 : d4[1];

        if (lane < 32) {
            const float4 cc = cst4[e];
            const float4 wx = wx4[e];
            const float2 wn = wn2[e];
            const float r0 = sigmoid_f(uR0 + fmaf(xv0.x, wx.x, fmaf(xv0.y, wx.y, cc.x)));
            const float z0 = sigmoid_f(uZ0 + fmaf(xv0.x, wx.z, fmaf(xv0.y, wx.w, cc.y)));
            const float n0 = tanh_f(fmaf(xv0.x, wn.x, fmaf(xv0.y, wn.y, cc.z)) + r0 * (uN0 + cc.w));
            float hn0 = fmaf(z0, hp0 - n0, n0);
            const float r1 = sigmoid_f(uR1 + fmaf(xv1.x, wx.x, fmaf(xv1.y, wx.y, cc.x)));
            const float z1 = sigmoid_f(uZ1 + fmaf(xv1.x, wx.z, fmaf(xv1.y, wx.w, cc.y)));
            const float n1 = tanh_f(fmaf(xv1.x, wn.x, fmaf(xv1.y, wn.y, cc.z)) + r1 * (uN1 + cc.w));
            float hn1 = fmaf(z1, hp1 - n1, n1);

            hn0 = (s < l0) ? hn0 : hp0;    // freeze finished batches
            hn1 = (s < l1) ? hn1 : hp1;
            const int nb = (s & 1) ^ 1;
            h16[nb][0][e] = (_Float16)hn0;
            h16[nb][1][e] = (_Float16)hn1;
            hp0 = hn0;
            hp1 = hn1;
            if (s == l0 - 1) out[b0 * HH + e] = hn0;
            if (s == l1 - 1) out[(b0 + 1) * HH + e] = hn1;
        }
        __syncthreads();   // new h16 buffer visible for next step's A reads
    }
}

extern "C" void kernel_launch(void* const* d_in, const int* in_sizes, int n_in,
                              void* d_out, int out_size, void* d_ws, size_t ws_size,
                              hipStream_t stream) {
    const float* x    = (const float*)d_in[0];
    const int*   lenp = (const int*)d_in[1];
    const float* h0   = (const float*)d_in[2];
    const float* Wih  = (const float*)d_in[3];
    const float* Whh  = (const float*)d_in[4];
    const float* bih  = (const float*)d_in[5];
    const float* bhh  = (const float*)d_in[6];
    float* out = (float*)d_out;

    uint4* Wp4 = (uint4*)d_ws;   // 384 KB scratch

    prep_pack<<<NT * KT * 64 / 256, 256, 0, stream>>>(Whh, Wp4);
    gru_persist<<<BB / 2, 512, 0, stream>>>(x, lenp, h0, Wih, bih, bhh, Wp4, out);
}